// Round 7
// baseline (206.344 us; speedup 1.0000x reference)
//
#include <hip/hip_runtime.h>
#include <math.h>

#define DIM 256

// ---------------------------------------------------------------------------
// Setup kernel: single thread computes the 3x4 voxel->voxel transform T and
// writes 12 floats to workspace.  T = inv(flo_v2r) @ T_rig @ ref_v2r, with
// T_rig = [[Rx@Ry@Rz, t],[0,0,0,1]]  (matches the JAX reference composition).
// ---------------------------------------------------------------------------

__device__ void matmul4(const float* A, const float* B, float* C) {
    for (int r = 0; r < 4; ++r)
        for (int c = 0; c < 4; ++c) {
            float acc = 0.f;
            for (int k = 0; k < 4; ++k) acc += A[r * 4 + k] * B[k * 4 + c];
            C[r * 4 + c] = acc;
        }
}

__device__ void invert4(const float* A, float* inv) {
    // Gauss-Jordan with partial pivoting on a [4][8] augmented matrix.
    float M[4][8];
    for (int r = 0; r < 4; ++r) {
        for (int c = 0; c < 4; ++c) M[r][c] = A[r * 4 + c];
        for (int c = 0; c < 4; ++c) M[r][4 + c] = (r == c) ? 1.f : 0.f;
    }
    for (int col = 0; col < 4; ++col) {
        int piv = col;
        float best = fabsf(M[col][col]);
        for (int r = col + 1; r < 4; ++r) {
            float v = fabsf(M[r][col]);
            if (v > best) { best = v; piv = r; }
        }
        if (piv != col)
            for (int c = 0; c < 8; ++c) {
                float t = M[col][c]; M[col][c] = M[piv][c]; M[piv][c] = t;
            }
        float d = 1.f / M[col][col];
        for (int c = 0; c < 8; ++c) M[col][c] *= d;
        for (int r = 0; r < 4; ++r) {
            if (r == col) continue;
            float f = M[r][col];
            for (int c = 0; c < 8; ++c) M[r][c] -= f * M[col][c];
        }
    }
    for (int r = 0; r < 4; ++r)
        for (int c = 0; c < 4; ++c) inv[r * 4 + c] = M[r][4 + c];
}

__global__ void compute_T_kernel(const float* __restrict__ rot,
                                 const float* __restrict__ trans,
                                 const float* __restrict__ ref_v2r,
                                 const float* __restrict__ flo_v2r,
                                 float* __restrict__ T_out) {
    if (threadIdx.x != 0 || blockIdx.x != 0) return;

    float cx = cosf(rot[0]), cy = cosf(rot[1]), cz = cosf(rot[2]);
    float sx = sinf(rot[0]), sy = sinf(rot[1]), sz = sinf(rot[2]);

    // Ry @ Rz
    float Ryz[3][3] = {
        { cy * cz, -cy * sz,  sy },
        { sz,       cz,       0.f },
        { -sy * cz, sy * sz,  cy }
    };
    // R = Rx @ (Ry @ Rz);  Rx = [[1,0,0],[0,cx,-sx],[0,sx,cx]]
    float R[3][3];
    for (int c = 0; c < 3; ++c) {
        R[0][c] = Ryz[0][c];
        R[1][c] = cx * Ryz[1][c] - sx * Ryz[2][c];
        R[2][c] = sx * Ryz[1][c] + cx * Ryz[2][c];
    }

    float Trig[16] = { R[0][0], R[0][1], R[0][2], trans[0],
                       R[1][0], R[1][1], R[1][2], trans[1],
                       R[2][0], R[2][1], R[2][2], trans[2],
                       0.f, 0.f, 0.f, 1.f };

    float ref[16], flo[16];
    for (int i = 0; i < 16; ++i) { ref[i] = ref_v2r[i]; flo[i] = flo_v2r[i]; }

    float inv_flo[16];
    invert4(flo, inv_flo);

    float M1[16];           // T_rig @ ref_v2r
    matmul4(Trig, ref, M1);
    float T[16];            // inv(flo) @ (T_rig @ ref_v2r)
    matmul4(inv_flo, M1, T);

    for (int i = 0; i < 12; ++i) T_out[i] = T[i];
}

// ---------------------------------------------------------------------------
// Warp kernel = R6 structure with unroll 2 -> 4 (the ONLY change).
//
//   - k = threadIdx.x (stride-1 lanes): each gather tap is 64 consecutive
//     floats = 4 cache lines/wave.  (R5: stride-4 lanes = 16 lines/instr
//     regressed badly.  Never break this.)
//   - XCD-slab sweep: block b -> XCD b&7, owns i-planes [xcd*32, +32);
//     per loop trip the XCD's 256 blocks cover planes iter..iter+3.
//   - 4 independent rows per trip in ONE basic block -> 32 gather loads
//     in flight per wave (R6 at unroll-2 was still 69% stall: VALUBusy
//     31%, hbm 11%).  Plain stores (nt-store was an R5 confound).
//   - Experiment isolation: R5={stride4,unroll4,nt}, R6={stride1,unroll2},
//     R7={stride1,unroll4}.  FETCH_SIZE is the footprint diagnostic.
// ---------------------------------------------------------------------------

__global__ __launch_bounds__(256)
void warp_trilinear_kernel(const float* __restrict__ X,
                           const float* __restrict__ Tm,
                           float* __restrict__ out) {
    __shared__ float T[12];
    if (threadIdx.x < 12) T[threadIdx.x] = Tm[threadIdx.x];
    __syncthreads();

    const float t00 = T[0], t01 = T[1], t02 = T[2], t03 = T[3];
    const float t10 = T[4], t11 = T[5], t12 = T[6], t13 = T[7];
    const float t20 = T[8], t21 = T[9], t22 = T[10], t23 = T[11];

    const int xcd = blockIdx.x & 7;       // assumed XCD id (round-robin)
    const int l   = blockIdx.x >> 3;      // 0..255: j-lane within the plane
    const int k   = threadIdx.x;          // 0..255: k coordinate (stride-1!)
    const float fk = (float)k;

    #pragma unroll 1
    for (int iter = 0; iter < 32; iter += 4) {
        float res[4];
        int rows[4];

        #pragma unroll
        for (int u = 0; u < 4; ++u) {
            const int row = (xcd << 13) + ((iter + u) << 8) + l; // i*256 + j
            rows[u] = row;
            const int i = row >> 8;
            const int j = row & 255;
            const float fi = (float)i, fj = (float)j;

            const float di = t00 * fi + t01 * fj + t02 * fk + t03;
            const float dj = t10 * fi + t11 * fj + t12 * fk + t13;
            const float dk = t20 * fi + t21 * fj + t22 * fk + t23;

            const bool ok = (di > 0.f) & (dj > 0.f) & (dk > 0.f) &
                            (di <= 255.f) & (dj <= 255.f) & (dk <= 255.f);

            const float fx = floorf(di), fy = floorf(dj), fz = floorf(dk);
            const float wcx = di - fx, wcy = dj - fy, wcz = dk - fz;
            const float wfx = 1.f - wcx, wfy = 1.f - wcy, wfz = 1.f - wcz;

            const int fxi = min(max((int)fx, 0), DIM - 1);
            const int fyi = min(max((int)fy, 0), DIM - 1);
            const int fzi = min(max((int)fz, 0), DIM - 1);
            const int cxi = min(max((int)fx + 1, 0), DIM - 1);
            const int cyi = min(max((int)fy + 1, 0), DIM - 1);
            const int czi = min(max((int)fz + 1, 0), DIM - 1);

            const int bff = (fxi << 16) + (fyi << 8);
            const int bfc = (fxi << 16) + (cyi << 8);
            const int bcf = (cxi << 16) + (fyi << 8);
            const int bcc = (cxi << 16) + (cyi << 8);

            const float v000 = X[bff + fzi];
            const float v001 = X[bff + czi];
            const float v010 = X[bfc + fzi];
            const float v011 = X[bfc + czi];
            const float v100 = X[bcf + fzi];
            const float v101 = X[bcf + czi];
            const float v110 = X[bcc + fzi];
            const float v111 = X[bcc + czi];

            const float wff = wfx * wfy, wfc = wfx * wcy;
            const float wcf = wcx * wfy, wcc = wcx * wcy;

            float val = v000 * (wff * wfz) + v001 * (wff * wcz) +
                        v010 * (wfc * wfz) + v011 * (wfc * wcz) +
                        v100 * (wcf * wfz) + v101 * (wcf * wcz) +
                        v110 * (wcc * wfz) + v111 * (wcc * wcz);

            res[u] = ok ? val : 0.f;
        }

        #pragma unroll
        for (int u = 0; u < 4; ++u)
            out[(rows[u] << 8) + k] = res[u];
    }
}

extern "C" void kernel_launch(void* const* d_in, const int* in_sizes, int n_in,
                              void* d_out, int out_size, void* d_ws, size_t ws_size,
                              hipStream_t stream) {
    const float* image   = (const float*)d_in[0];  // [1,1,256,256,256]
    const float* rot     = (const float*)d_in[1];  // [1,3]
    const float* trans   = (const float*)d_in[2];  // [1,3]
    const float* ref_v2r = (const float*)d_in[3];  // [4,4]
    const float* flo_v2r = (const float*)d_in[4];  // [4,4]
    float* out = (float*)d_out;
    float* Tws = (float*)d_ws;                     // 12 floats

    compute_T_kernel<<<1, 64, 0, stream>>>(rot, trans, ref_v2r, flo_v2r, Tws);

    // 2048 blocks x 256 threads; each block does 32 rows (4 per loop trip).
    warp_trilinear_kernel<<<2048, 256, 0, stream>>>(image, Tws, out);
}

// Round 8
// 183.968 us; speedup vs baseline: 1.1216x; 1.1216x over previous
//
#include <hip/hip_runtime.h>
#include <math.h>

#define DIM 256

// 8-byte vector with 4-byte alignment promise: legal at odd z offsets.
// If unaligned dwordx2 were unsupported, clang would split it (= status quo).
typedef float f2v __attribute__((ext_vector_type(2), aligned(4)));

// ---------------------------------------------------------------------------
// Setup kernel: single thread computes the 3x4 voxel->voxel transform T and
// writes 12 floats to workspace.  T = inv(flo_v2r) @ T_rig @ ref_v2r, with
// T_rig = [[Rx@Ry@Rz, t],[0,0,0,1]]  (matches the JAX reference composition).
// ---------------------------------------------------------------------------

__device__ void matmul4(const float* A, const float* B, float* C) {
    for (int r = 0; r < 4; ++r)
        for (int c = 0; c < 4; ++c) {
            float acc = 0.f;
            for (int k = 0; k < 4; ++k) acc += A[r * 4 + k] * B[k * 4 + c];
            C[r * 4 + c] = acc;
        }
}

__device__ void invert4(const float* A, float* inv) {
    // Gauss-Jordan with partial pivoting on a [4][8] augmented matrix.
    float M[4][8];
    for (int r = 0; r < 4; ++r) {
        for (int c = 0; c < 4; ++c) M[r][c] = A[r * 4 + c];
        for (int c = 0; c < 4; ++c) M[r][4 + c] = (r == c) ? 1.f : 0.f;
    }
    for (int col = 0; col < 4; ++col) {
        int piv = col;
        float best = fabsf(M[col][col]);
        for (int r = col + 1; r < 4; ++r) {
            float v = fabsf(M[r][col]);
            if (v > best) { best = v; piv = r; }
        }
        if (piv != col)
            for (int c = 0; c < 8; ++c) {
                float t = M[col][c]; M[col][c] = M[piv][c]; M[piv][c] = t;
            }
        float d = 1.f / M[col][col];
        for (int c = 0; c < 8; ++c) M[col][c] *= d;
        for (int r = 0; r < 4; ++r) {
            if (r == col) continue;
            float f = M[r][col];
            for (int c = 0; c < 8; ++c) M[r][c] -= f * M[col][c];
        }
    }
    for (int r = 0; r < 4; ++r)
        for (int c = 0; c < 4; ++c) inv[r * 4 + c] = M[r][4 + c];
}

__global__ void compute_T_kernel(const float* __restrict__ rot,
                                 const float* __restrict__ trans,
                                 const float* __restrict__ ref_v2r,
                                 const float* __restrict__ flo_v2r,
                                 float* __restrict__ T_out) {
    if (threadIdx.x != 0 || blockIdx.x != 0) return;

    float cx = cosf(rot[0]), cy = cosf(rot[1]), cz = cosf(rot[2]);
    float sx = sinf(rot[0]), sy = sinf(rot[1]), sz = sinf(rot[2]);

    // Ry @ Rz
    float Ryz[3][3] = {
        { cy * cz, -cy * sz,  sy },
        { sz,       cz,       0.f },
        { -sy * cz, sy * sz,  cy }
    };
    // R = Rx @ (Ry @ Rz);  Rx = [[1,0,0],[0,cx,-sx],[0,sx,cx]]
    float R[3][3];
    for (int c = 0; c < 3; ++c) {
        R[0][c] = Ryz[0][c];
        R[1][c] = cx * Ryz[1][c] - sx * Ryz[2][c];
        R[2][c] = sx * Ryz[1][c] + cx * Ryz[2][c];
    }

    float Trig[16] = { R[0][0], R[0][1], R[0][2], trans[0],
                       R[1][0], R[1][1], R[1][2], trans[1],
                       R[2][0], R[2][1], R[2][2], trans[2],
                       0.f, 0.f, 0.f, 1.f };

    float ref[16], flo[16];
    for (int i = 0; i < 16; ++i) { ref[i] = ref_v2r[i]; flo[i] = flo_v2r[i]; }

    float inv_flo[16];
    invert4(flo, inv_flo);

    float M1[16];           // T_rig @ ref_v2r
    matmul4(Trig, ref, M1);
    float T[16];            // inv(flo) @ (T_rig @ ref_v2r)
    matmul4(inv_flo, M1, T);

    for (int i = 0; i < 12; ++i) T_out[i] = T[i];
}

// ---------------------------------------------------------------------------
// Warp kernel = R6 structure (113 us) with z-pair dwordx2 gathers.
//
//   - k = threadIdx.x (stride-1 lanes).  R5 lesson: never break this.
//   - XCD-slab sweep (block b -> XCD b&7): FETCH 470 -> 33 MB (R3).
//   - R6/R7 lesson: compiler pins VGPR=32 and serializes load batches;
//     waves are ~90% blocked on s_waitcnt (VALUBusy 30%, hbm 11%).
//     Limiter = gather instruction count x wait rounds.
//   - NEW: (fz,cz) taps are adjacent -> one 8B load per (x,y) corner:
//       zb = min(fzi,254);  v = {X[b+zb], X[b+zb+1]}
//       vf = (fzi==255) ? v.y : v.x     (dk<=255 => weight-exact)
//       vc = v.y                        (czi = min(fzi+1,255))
//     Bit-identical tap values, always in-bounds, 8 loads -> 4,
//     address VALU halved.
// ---------------------------------------------------------------------------

__global__ __launch_bounds__(256)
void warp_trilinear_kernel(const float* __restrict__ X,
                           const float* __restrict__ Tm,
                           float* __restrict__ out) {
    __shared__ float T[12];
    if (threadIdx.x < 12) T[threadIdx.x] = Tm[threadIdx.x];
    __syncthreads();

    const float t00 = T[0], t01 = T[1], t02 = T[2], t03 = T[3];
    const float t10 = T[4], t11 = T[5], t12 = T[6], t13 = T[7];
    const float t20 = T[8], t21 = T[9], t22 = T[10], t23 = T[11];

    const int xcd = blockIdx.x & 7;       // assumed XCD id (round-robin)
    const int l   = blockIdx.x >> 3;      // 0..255: j-lane within the plane
    const int k   = threadIdx.x;          // 0..255: k coordinate (stride-1!)
    const float fk = (float)k;

    #pragma unroll 1
    for (int iter = 0; iter < 32; iter += 2) {
        float res[2];
        int rows[2];

        #pragma unroll
        for (int u = 0; u < 2; ++u) {
            const int row = (xcd << 13) + ((iter + u) << 8) + l; // i*256 + j
            rows[u] = row;
            const int i = row >> 8;
            const int j = row & 255;
            const float fi = (float)i, fj = (float)j;

            const float di = t00 * fi + t01 * fj + t02 * fk + t03;
            const float dj = t10 * fi + t11 * fj + t12 * fk + t13;
            const float dk = t20 * fi + t21 * fj + t22 * fk + t23;

            const bool ok = (di > 0.f) & (dj > 0.f) & (dk > 0.f) &
                            (di <= 255.f) & (dj <= 255.f) & (dk <= 255.f);

            const float fx = floorf(di), fy = floorf(dj), fz = floorf(dk);
            const float wcx = di - fx, wcy = dj - fy, wcz = dk - fz;
            const float wfx = 1.f - wcx, wfy = 1.f - wcy, wfz = 1.f - wcz;

            const int fxi = min(max((int)fx, 0), DIM - 1);
            const int fyi = min(max((int)fy, 0), DIM - 1);
            const int fzi = min(max((int)fz, 0), DIM - 1);
            const int cxi = min(max((int)fx + 1, 0), DIM - 1);
            const int cyi = min(max((int)fy + 1, 0), DIM - 1);

            const int bff = (fxi << 16) + (fyi << 8);
            const int bfc = (fxi << 16) + (cyi << 8);
            const int bcf = (cxi << 16) + (fyi << 8);
            const int bcc = (cxi << 16) + (cyi << 8);

            // z-pair loads: zb in [0,254], so [b+zb, b+zb+1] stays inside
            // the 256-float row for every lane (masked ones included).
            const int  zb   = min(fzi, DIM - 2);
            const bool zhi  = (fzi == DIM - 1);   // only when dk == 255 (w=0)

            const f2v pff = *(const f2v*)(X + bff + zb);
            const f2v pfc = *(const f2v*)(X + bfc + zb);
            const f2v pcf = *(const f2v*)(X + bcf + zb);
            const f2v pcc = *(const f2v*)(X + bcc + zb);

            const float v000 = zhi ? pff.y : pff.x;  // (xf,yf,zf)
            const float v001 = pff.y;                // (xf,yf,zc)
            const float v010 = zhi ? pfc.y : pfc.x;  // (xf,yc,zf)
            const float v011 = pfc.y;                // (xf,yc,zc)
            const float v100 = zhi ? pcf.y : pcf.x;  // (xc,yf,zf)
            const float v101 = pcf.y;                // (xc,yf,zc)
            const float v110 = zhi ? pcc.y : pcc.x;  // (xc,yc,zf)
            const float v111 = pcc.y;                // (xc,yc,zc)

            const float wff = wfx * wfy, wfc = wfx * wcy;
            const float wcf = wcx * wfy, wcc = wcx * wcy;

            float val = v000 * (wff * wfz) + v001 * (wff * wcz) +
                        v010 * (wfc * wfz) + v011 * (wfc * wcz) +
                        v100 * (wcf * wfz) + v101 * (wcf * wcz) +
                        v110 * (wcc * wfz) + v111 * (wcc * wcz);

            res[u] = ok ? val : 0.f;
        }

        out[(rows[0] << 8) + k] = res[0];
        out[(rows[1] << 8) + k] = res[1];
    }
}

extern "C" void kernel_launch(void* const* d_in, const int* in_sizes, int n_in,
                              void* d_out, int out_size, void* d_ws, size_t ws_size,
                              hipStream_t stream) {
    const float* image   = (const float*)d_in[0];  // [1,1,256,256,256]
    const float* rot     = (const float*)d_in[1];  // [1,3]
    const float* trans   = (const float*)d_in[2];  // [1,3]
    const float* ref_v2r = (const float*)d_in[3];  // [4,4]
    const float* flo_v2r = (const float*)d_in[4];  // [4,4]
    float* out = (float*)d_out;
    float* Tws = (float*)d_ws;                     // 12 floats

    compute_T_kernel<<<1, 64, 0, stream>>>(rot, trans, ref_v2r, flo_v2r, Tws);

    // 2048 blocks x 256 threads; each block does 32 rows (2 per loop trip).
    warp_trilinear_kernel<<<2048, 256, 0, stream>>>(image, Tws, out);
}